// Round 9
// baseline (37.908 us; speedup 1.0000x reference)
//
#include <hip/hip_runtime.h>
#include <hip/hip_bf16.h>

#define TT 2048
#define HH 1024
#define NTAGS 74
#define NPAD 80
#define CHK 32            // K elements per chunk
#define NCH (HH / CHK)    // 32 chunks
#define MROWS 64          // rows per block
#define THREADS 256

typedef __bf16 bf16x8 __attribute__((ext_vector_type(8)));
typedef float f32x4 __attribute__((ext_vector_type(4)));

// async global->LDS, 16B per lane; LDS dest = wave-uniform base + lane*16
__device__ __forceinline__ void gl_lds16(const void* g, void* l) {
    __builtin_amdgcn_global_load_lds((const __attribute__((address_space(1))) void*)g,
                                     (__attribute__((address_space(3))) void*)l, 16, 0, 0);
}

// Transpose + convert W_out [1024][74] f32 -> Wt [80][1024] bf16 (pad cols 74..79 = 0)
__global__ __launch_bounds__(256) void prep_w_kernel(const float* __restrict__ W,
                                                     __bf16* __restrict__ Wt) {
    __shared__ float tile[64][80];
    const int k0 = blockIdx.x * 64;
    const int tid = threadIdx.x;
    for (int i = tid; i < 64 * NTAGS; i += 256) {
        int k = i / NTAGS, n = i - k * NTAGS;
        tile[k][n] = W[(k0 + k) * NTAGS + n];
    }
    __syncthreads();
    for (int i = tid; i < NPAD * 64; i += 256) {
        int n = i >> 6, kk = i & 63;
        float v = (n < NTAGS) ? tile[kk][n] : 0.0f;
        Wt[n * HH + k0 + kk] = (__bf16)v;
    }
}

// R9: async-staged fused gather-blend + GEMM. Block = 256 thr (4 waves), M=64,
// grid 512 (2 blocks/CU). CHK=32, 3-slot rotating LDS (char 3x8K @0, word 3x8K
// @24576, W 3x5K @49152 = 63KB). Staging = 6x global_load_lds(16B)/thread/chunk,
// uniform per wave -> deterministic counted vmcnt(6) (never 0 in steady state).
// Loop: {vmcnt(6); s_barrier} -> STAGE(ch+2) -> compute(ch). Stage slot
// (ch+2)%3 == (ch-1)%3 is free after the barrier (readers of ch-1 passed it).
// LDS linear (gload_lds constraint); swizzle via pre-swizzled GLOBAL source:
// char/word piece (row,u) holds global unit u^(row&7); W unit u^((n>>1)&3).
// Blend at fragment build with the lane's own-row rate (rate=0 zeroes invalid
// rows); invalid staged rows load batch-row-0 (L1-hot) to keep counts exact.
__global__ __launch_bounds__(256, 2) void slu_main(const float* __restrict__ out_char,
                                                   const float* __restrict__ out_word,
                                                   const int* __restrict__ word_idx,
                                                   const int* __restrict__ is_head,
                                                   const int* __restrict__ valid_mask,
                                                   const __bf16* __restrict__ Wt,
                                                   const float* __restrict__ b_out,
                                                   float* __restrict__ out) {
    __shared__ __align__(16) char smem[64512];
    const int tid = threadIdx.x;
    const int wv = tid >> 6;
    const int lane = tid & 63;
    const int l15 = lane & 15;
    const int kgrp = lane >> 4;
    const int rowbase = blockIdx.x * MROWS;
    const int batch = rowbase >> 11;  // T = 2048
    const size_t batbase = (size_t)batch * TT;

    // ---- my MFMA row's blend params (lane owns row wv*16+l15) ----
    const int myrow = rowbase + wv * 16 + l15;
    const int myval = valid_mask[myrow];
    const float myrt = is_head[myrow] ? 0.88f : 0.70f;
    const float rate = myval ? myrt : 0.0f;
    const float crate = myval ? (1.0f - myrt) : 0.0f;

    // ---- staging descriptors: rows srow0=tid>>3, srow1=srow0+32; 16B piece su ----
    const int srow0 = tid >> 3, srow1 = srow0 + 32;
    const int su = (tid & 7) ^ (srow0 & 7);  // srow1&7 == srow0&7
    const int r0 = rowbase + srow0, r1 = rowbase + srow1;
    const size_t cr0 = valid_mask[r0] ? (size_t)r0 : batbase;  // invalid -> hot row 0
    const size_t cr1 = valid_mask[r1] ? (size_t)r1 : batbase;
    const float* c_src0 = out_char + cr0 * HH + su * 4;
    const float* c_src1 = out_char + cr1 * HH + su * 4;
    const float* w_src0 = out_word + (batbase + word_idx[r0]) * HH + su * 4;
    const float* w_src1 = out_word + (batbase + word_idx[r1]) * HH + su * 4;

    // ---- W staging: 320 16B-units/chunk; wave w owns units w*80..w*80+79 ----
    const int uA = wv * 80 + lane;
    const int nA = uA >> 2, usA = (uA & 3) ^ ((nA >> 1) & 3);
    const __bf16* wt_srcA = Wt + (size_t)nA * HH + usA * 8;
    const int uB = wv * 80 + 64 + lane;  // only lanes 0..15 issue
    const int nB = uB >> 2, usB = (uB & 3) ^ ((nB >> 1) & 3);
    const __bf16* wt_srcB = Wt + (size_t)nB * HH + usB * 8;

    // ---- fragment read offsets (match the source pre-swizzle) ----
    const int arow = wv * 16 + l15;
    const int sw = l15 & 7;
    const int cfo0 = arow * 128 + (((kgrp << 1)) ^ sw) * 16;
    const int cfo1 = arow * 128 + (((kgrp << 1) | 1) ^ sw) * 16;
    int wto[5];
#pragma unroll
    for (int nt = 0; nt < 5; ++nt) {
        const int n = nt * 16 + l15;
        wto[nt] = n * 64 + (kgrp ^ ((n >> 1) & 3)) * 16;
    }

    f32x4 acc[5];
#pragma unroll
    for (int nt = 0; nt < 5; ++nt) acc[nt] = (f32x4){0.f, 0.f, 0.f, 0.f};

    // ---- staging: 6 loads/thread, uniform count per wave ----
    auto STAGE = [&](int ch, int s) {
        const int kc = ch * CHK;  // elems (f32 for char/word, bf16 for W)
        char* cb = smem + s * 8192;
        char* wb = smem + 24576 + s * 8192;
        char* wtb = smem + 49152 + s * 5120;
        gl_lds16(c_src0 + kc, cb + wv * 1024);
        gl_lds16(c_src1 + kc, cb + 4096 + wv * 1024);
        gl_lds16(w_src0 + kc, wb + wv * 1024);
        gl_lds16(w_src1 + kc, wb + 4096 + wv * 1024);
        gl_lds16(wt_srcA + kc, wtb + wv * 1280);
        if (lane < 16) gl_lds16(wt_srcB + kc, wtb + wv * 1280 + 1024);
    };

    STAGE(0, 0);
    STAGE(1, 1);

    int s = 0, s2 = 2;
    for (int ch = 0; ch < NCH; ++ch) {
        // wait for chunk ch's 6 loads (leave ch+1's 6 in flight), then barrier
        if (ch + 1 < NCH) {
            asm volatile("s_waitcnt vmcnt(6)\n\ts_barrier" ::: "memory");
        } else {
            asm volatile("s_waitcnt vmcnt(0)\n\ts_barrier" ::: "memory");
        }
        // prefetch chunk ch+2 into slot (ch+2)%3 (free: its readers passed the barrier)
        if (ch + 2 < NCH) STAGE(ch + 2, s2);

        // compute chunk ch from slot s
        const char* cb = smem + s * 8192;
        const char* wb = smem + 24576 + s * 8192;
        const char* wtb = smem + 49152 + s * 5120;
        const float4 c0 = *(const float4*)(cb + cfo0);
        const float4 c1 = *(const float4*)(cb + cfo1);
        const float4 g0 = *(const float4*)(wb + cfo0);
        const float4 g1 = *(const float4*)(wb + cfo1);
        bf16x8 a;
        a[0] = (__bf16)(g0.x * rate + c0.x * crate);
        a[1] = (__bf16)(g0.y * rate + c0.y * crate);
        a[2] = (__bf16)(g0.z * rate + c0.z * crate);
        a[3] = (__bf16)(g0.w * rate + c0.w * crate);
        a[4] = (__bf16)(g1.x * rate + c1.x * crate);
        a[5] = (__bf16)(g1.y * rate + c1.y * crate);
        a[6] = (__bf16)(g1.z * rate + c1.z * crate);
        a[7] = (__bf16)(g1.w * rate + c1.w * crate);
#pragma unroll
        for (int nt = 0; nt < 5; ++nt) {
            bf16x8 bw = *(const bf16x8*)(wtb + wto[nt]);
            acc[nt] = __builtin_amdgcn_mfma_f32_16x16x32_bf16(a, bw, acc[nt], 0, 0, 0);
        }
        s = (s == 2) ? 0 : s + 1;
        s2 = (s2 == 2) ? 0 : s2 + 1;
    }

    // ---- epilogue: C/D col = lane&15, row = (lane>>4)*4 + reg  [verified R2-R8] ----
    const int orow = rowbase + wv * 16 + kgrp * 4;
#pragma unroll
    for (int nt = 0; nt < 5; ++nt) {
        const int col = nt * 16 + l15;
        if (col < NTAGS) {
            const float bias = b_out[col];
#pragma unroll
            for (int i = 0; i < 4; ++i) {
                out[(size_t)(orow + i) * NTAGS + col] = acc[nt][i] + bias;
            }
        }
    }
}

extern "C" void kernel_launch(void* const* d_in, const int* in_sizes, int n_in,
                              void* d_out, int out_size, void* d_ws, size_t ws_size,
                              hipStream_t stream) {
    const float* out_char = (const float*)d_in[0];
    const float* out_word = (const float*)d_in[1];
    const int* word_idx = (const int*)d_in[2];
    const int* is_head = (const int*)d_in[3];
    const int* valid_mask = (const int*)d_in[4];
    const float* W_out = (const float*)d_in[5];
    const float* b_out = (const float*)d_in[6];
    float* out = (float*)d_out;
    __bf16* Wt = (__bf16*)d_ws;  // 80*1024*2 = 160 KB

    prep_w_kernel<<<HH / 64, 256, 0, stream>>>(W_out, Wt);

    const int rows = 16 * TT;  // B*T = 32768
    slu_main<<<rows / MROWS, THREADS, 0, stream>>>(out_char, out_word, word_idx, is_head,
                                                   valid_mask, Wt, b_out, out);
}